// Round 1
// baseline (132.231 us; speedup 1.0000x reference)
//
#include <hip/hip_runtime.h>
#include <math.h>

// Problem dims (fixed by setup_inputs): B=8, N=1024 -> ROWS=8192; M=2048; E=256; H1=32; H2=16
#define ROWS 8192
#define M_TOTAL 2048
#define E_DIM 256
#define H1 32
#define H2 16

__device__ __forceinline__ float gelu_exact(float x) {
    // jax.nn.gelu(approximate=False): x * 0.5 * (1 + erf(x/sqrt(2)))
    return 0.5f * x * (1.0f + erff(x * 0.70710678118654752f));
}

// One wave (64 lanes) computes sigma for 4 rows; w1 element loaded once, reused 4x.
__global__ __launch_bounds__(64) void sigma_mlp_kernel(
    const float* __restrict__ emb,
    const float* __restrict__ w1, const float* __restrict__ b1,
    const float* __restrict__ w2, const float* __restrict__ b2,
    const float* __restrict__ w3, const float* __restrict__ b3,
    float* __restrict__ c_out)
{
    __shared__ float se[4][E_DIM];
    __shared__ float sh1[4][H1];
    const int lane = threadIdx.x;
    const int row0 = blockIdx.x * 4;

    // Stage 4 embedding rows into LDS (float4 coalesced).
    const float4* e4 = (const float4*)emb;
    #pragma unroll
    for (int r = 0; r < 4; ++r) {
        float4 v = e4[(size_t)(row0 + r) * (E_DIM / 4) + lane];
        ((float4*)se[r])[lane] = v;
    }
    __syncthreads();

    // ---- Layer 1: 256 -> 32, lanes split as (o = lane&31, half = lane>>5) ----
    const int o = lane & 31;
    const int half = lane >> 5;
    const int kbase = half * 128;
    float acc0 = 0.f, acc1 = 0.f, acc2 = 0.f, acc3 = 0.f;
    for (int k = 0; k < 128; ++k) {
        const int kk = kbase + k;
        const float w = w1[kk * H1 + o];      // 32 consecutive floats/half: L1-friendly
        acc0 = fmaf(se[0][kk], w, acc0);      // LDS broadcast reads (conflict-free)
        acc1 = fmaf(se[1][kk], w, acc1);
        acc2 = fmaf(se[2][kk], w, acc2);
        acc3 = fmaf(se[3][kk], w, acc3);
    }
    const float b1v = b1[o];
    float h1v[4] = {acc0, acc1, acc2, acc3};
    #pragma unroll
    for (int r = 0; r < 4; ++r) {
        float v = h1v[r] + __shfl_xor(h1v[r], 32);   // combine the two K-halves
        v = gelu_exact(v + b1v);
        if (half == 0) sh1[r][o] = v;
    }
    __syncthreads();

    // ---- Layer 2: 32 -> 16, lanes split as (o2 = lane&15, q = lane>>4) ----
    const int o2 = lane & 15;
    const int q = lane >> 4;
    float a2[4] = {0.f, 0.f, 0.f, 0.f};
    #pragma unroll
    for (int j = 0; j < 8; ++j) {
        const int k = q * 8 + j;
        const float w = w2[k * H2 + o2];
        #pragma unroll
        for (int r = 0; r < 4; ++r) a2[r] = fmaf(sh1[r][k], w, a2[r]);
    }
    const float b2v = b2[o2];
    const float w3v = w3[o2];
    float a3[4];
    #pragma unroll
    for (int r = 0; r < 4; ++r) {
        float v = a2[r];
        v += __shfl_xor(v, 16);   // sum the 4 q-groups
        v += __shfl_xor(v, 32);
        v = gelu_exact(v + b2v);
        // ---- Layer 3: 16 -> 1 ----
        float t = v * w3v;
        t += __shfl_xor(t, 1);
        t += __shfl_xor(t, 2);
        t += __shfl_xor(t, 4);
        t += __shfl_xor(t, 8);
        a3[r] = t;                // every lane now holds the full dot for row r
    }

    if (lane < 4) {
        const float b3v = b3[0];
        float x = (lane == 0) ? a3[0] : (lane == 1) ? a3[1] : (lane == 2) ? a3[2] : a3[3];
        x += b3v;
        const float s = 1.0f / (1.0f + __expf(-x));   // sigmoid
        const float sigma = 0.1f + 9.9f * s;          // MIN + (MAX-MIN)*s
        c_out[row0 + lane] = -0.5f / (sigma * sigma); // exp coefficient (natural log)
    }
}

// One block per (b,n) row; 256 threads x 8 m-values each; float4 loads/stores.
__global__ __launch_bounds__(256) void rbf_kernel(
    const float* __restrict__ z, const float* __restrict__ mu,
    const float* __restrict__ c_in, float* __restrict__ out)
{
    const int row = blockIdx.x;
    const int t = threadIdx.x;
    const float c = c_in[row];                 // wave-uniform
    const float mu0 = mu[row * 2 + 0];
    const float mu1 = mu[row * 2 + 1];
    const float4* zf4 = (const float4*)z;      // z[M][2]: float4 j = (z[2j][0..1], z[2j+1][0..1])
    float4* out4 = (float4*)out + (size_t)row * (M_TOTAL / 4);

    #pragma unroll
    for (int i = 0; i < 2; ++i) {
        const int idx = i * 256 + t;           // float4 index within the row: 0..511
        const float4 za = zf4[idx * 2 + 0];    // m = 4*idx + {0,1}
        const float4 zb = zf4[idx * 2 + 1];    // m = 4*idx + {2,3}
        float4 r;
        float d0, d1;
        d0 = za.x - mu0; d1 = za.y - mu1;
        r.x = __expf(fmaf(d1, d1, d0 * d0) * c);
        d0 = za.z - mu0; d1 = za.w - mu1;
        r.y = __expf(fmaf(d1, d1, d0 * d0) * c);
        d0 = zb.x - mu0; d1 = zb.y - mu1;
        r.z = __expf(fmaf(d1, d1, d0 * d0) * c);
        d0 = zb.z - mu0; d1 = zb.w - mu1;
        r.w = __expf(fmaf(d1, d1, d0 * d0) * c);
        out4[idx] = r;                         // coalesced 16B stores
    }
}

extern "C" void kernel_launch(void* const* d_in, const int* in_sizes, int n_in,
                              void* d_out, int out_size, void* d_ws, size_t ws_size,
                              hipStream_t stream) {
    const float* z   = (const float*)d_in[0];
    const float* mu  = (const float*)d_in[1];
    const float* emb = (const float*)d_in[2];
    const float* w1  = (const float*)d_in[3];
    const float* b1  = (const float*)d_in[4];
    const float* w2  = (const float*)d_in[5];
    const float* b2  = (const float*)d_in[6];
    const float* w3  = (const float*)d_in[7];
    const float* b3  = (const float*)d_in[8];
    float* out = (float*)d_out;
    float* c_ws = (float*)d_ws;   // 8192 floats = 32 KiB of scratch

    sigma_mlp_kernel<<<ROWS / 4, 64, 0, stream>>>(emb, w1, b1, w2, b2, w3, b3, c_ws);
    rbf_kernel<<<ROWS, 256, 0, stream>>>(z, mu, c_ws, out);
}

// Round 2
// 107.518 us; speedup vs baseline: 1.2299x; 1.2299x over previous
//
#include <hip/hip_runtime.h>
#include <math.h>

// Problem dims (fixed by setup_inputs): B=8, N=1024 -> ROWS=8192; M=2048; E=256; H1=32; H2=16
#define ROWS 8192
#define M_TOTAL 2048
#define E_DIM 256
#define H1 32
#define H2 16

__device__ __forceinline__ float gelu_exact(float x) {
    // jax.nn.gelu(approximate=False): x * 0.5 * (1 + erf(x/sqrt(2)))
    return 0.5f * x * (1.0f + erff(x * 0.70710678118654752f));
}

// One block per (b,n) row. Phase 1: compute this row's sigma via the tiny MLP
// with all 256 threads. Phase 2: RBF over M=2048 with float4 loads/stores.
__global__ __launch_bounds__(256) void fused_rbf_kernel(
    const float* __restrict__ z, const float* __restrict__ mu,
    const float* __restrict__ emb,
    const float* __restrict__ w1, const float* __restrict__ b1,
    const float* __restrict__ w2, const float* __restrict__ b2,
    const float* __restrict__ w3, const float* __restrict__ b3,
    float* __restrict__ out)
{
    __shared__ float se[E_DIM];     // embedding row
    __shared__ float red[8][H1];    // layer-1 chunk partials
    __shared__ float h1s[H1];
    __shared__ float h2s[H2];
    __shared__ float csh;

    const int row = blockIdx.x;
    const int t = threadIdx.x;

    // ---- Stage e-row: 256 threads x 1 float, coalesced ----
    se[t] = emb[(size_t)row * E_DIM + t];
    __syncthreads();

    // ---- Layer 1: 256 -> 32. thread = (o = t&31, chunk = t>>5); 32 FMA each ----
    {
        const int o = t & 31;
        const int chunk = t >> 5;
        const int k0 = chunk * 32;
        float acc = 0.f;
        #pragma unroll
        for (int j = 0; j < 32; ++j) {
            const int k = k0 + j;
            acc = fmaf(se[k], w1[k * H1 + o], acc);  // se: broadcast; w1: L1-warm 128B/half-wave
        }
        red[chunk][o] = acc;
    }
    __syncthreads();

    if (t < H1) {
        float h = red[0][t] + red[1][t] + red[2][t] + red[3][t]
                + red[4][t] + red[5][t] + red[6][t] + red[7][t];
        h1s[t] = gelu_exact(h + b1[t]);
    }
    __syncthreads();

    // ---- Layer 2: 32 -> 16 ----
    if (t < H2) {
        float a = 0.f;
        #pragma unroll
        for (int k = 0; k < H1; ++k) a = fmaf(h1s[k], w2[k * H2 + t], a);
        h2s[t] = gelu_exact(a + b2[t]);
    }
    __syncthreads();

    // ---- Layer 3: 16 -> 1, sigmoid, sigma -> c = -0.5/sigma^2 ----
    if (t == 0) {
        float sum = 0.f;
        #pragma unroll
        for (int k = 0; k < H2; ++k) sum = fmaf(h2s[k], w3[k], sum);
        const float x = sum + b3[0];
        const float s = 1.0f / (1.0f + __expf(-x));
        const float sigma = 0.1f + 9.9f * s;
        csh = -0.5f / (sigma * sigma);
    }
    __syncthreads();

    // ---- Phase 2: RBF over m. 256 threads x 8 m-values, float4 I/O ----
    const float c = csh;
    const float mu0 = mu[row * 2 + 0];
    const float mu1 = mu[row * 2 + 1];
    const float4* zf4 = (const float4*)z;      // z[M][2]: float4 j = (z[2j][.], z[2j+1][.])
    float4* out4 = (float4*)out + (size_t)row * (M_TOTAL / 4);

    #pragma unroll
    for (int i = 0; i < 2; ++i) {
        const int idx = i * 256 + t;           // float4 index within the row: 0..511
        const float4 za = zf4[idx * 2 + 0];    // m = 4*idx + {0,1}
        const float4 zb = zf4[idx * 2 + 1];    // m = 4*idx + {2,3}
        float4 r;
        float d0, d1;
        d0 = za.x - mu0; d1 = za.y - mu1;
        r.x = __expf(fmaf(d1, d1, d0 * d0) * c);
        d0 = za.z - mu0; d1 = za.w - mu1;
        r.y = __expf(fmaf(d1, d1, d0 * d0) * c);
        d0 = zb.x - mu0; d1 = zb.y - mu1;
        r.z = __expf(fmaf(d1, d1, d0 * d0) * c);
        d0 = zb.z - mu0; d1 = zb.w - mu1;
        r.w = __expf(fmaf(d1, d1, d0 * d0) * c);
        out4[idx] = r;                         // coalesced 16B stores
    }
}

extern "C" void kernel_launch(void* const* d_in, const int* in_sizes, int n_in,
                              void* d_out, int out_size, void* d_ws, size_t ws_size,
                              hipStream_t stream) {
    const float* z   = (const float*)d_in[0];
    const float* mu  = (const float*)d_in[1];
    const float* emb = (const float*)d_in[2];
    const float* w1  = (const float*)d_in[3];
    const float* b1  = (const float*)d_in[4];
    const float* w2  = (const float*)d_in[5];
    const float* b2  = (const float*)d_in[6];
    const float* w3  = (const float*)d_in[7];
    const float* b3  = (const float*)d_in[8];
    float* out = (float*)d_out;

    fused_rbf_kernel<<<ROWS, 256, 0, stream>>>(z, mu, emb, w1, b1, w2, b2, w3, b3, out);
}

// Round 3
// 105.517 us; speedup vs baseline: 1.2532x; 1.0190x over previous
//
#include <hip/hip_runtime.h>
#include <math.h>

// Problem dims (fixed by setup_inputs): B=8, N=1024 -> ROWS=8192; M=2048; E=256; H1=32; H2=16
#define ROWS 8192
#define M_TOTAL 2048
#define E_DIM 256
#define H1 32
#define H2 16
#define R_PER_BLK 32   // rows per MLP block; 256 blocks total = 1 per CU

__device__ __forceinline__ float gelu_exact(float x) {
    // jax.nn.gelu(approximate=False): x * 0.5 * (1 + erf(x/sqrt(2)))
    return 0.5f * x * (1.0f + erff(x * 0.70710678118654752f));
}

// 256 blocks x 256 threads; each block computes sigma for 32 rows.
// w1 (32KB) + 32 emb rows (32KB) staged in LDS once per block.
__global__ __launch_bounds__(256) void sigma_mlp_v2(
    const float* __restrict__ emb,
    const float* __restrict__ w1, const float* __restrict__ b1,
    const float* __restrict__ w2, const float* __restrict__ b2,
    const float* __restrict__ w3, const float* __restrict__ b3,
    float* __restrict__ c_out)
{
    __shared__ float se[R_PER_BLK * E_DIM];     // 32 rows x 256, flat
    __shared__ float sw1[E_DIM * H1];           // w1[k][o], flat
    __shared__ float sh1[R_PER_BLK][H1 + 1];
    __shared__ float sh2[R_PER_BLK][H2 + 1];

    const int t = threadIdx.x;
    const int row0 = blockIdx.x * R_PER_BLK;

    // ---- Stage: flat float4 copies, fully coalesced ----
    {
        const float4* src_e = (const float4*)(emb + (size_t)row0 * E_DIM);
        float4* dst_e = (float4*)se;
        const float4* src_w = (const float4*)w1;
        float4* dst_w = (float4*)sw1;
        #pragma unroll
        for (int i = 0; i < 8; ++i) {           // 2048 float4 each / 256 threads
            dst_e[t + 256 * i] = src_e[t + 256 * i];
            dst_w[t + 256 * i] = src_w[t + 256 * i];
        }
    }
    __syncthreads();

    // ---- Layer 1: 256 -> 32. thread = (o = t&31, g = t>>5) -> rows 4g..4g+3, full K ----
    {
        const int o = t & 31;
        const int g = t >> 5;
        float acc0 = 0.f, acc1 = 0.f, acc2 = 0.f, acc3 = 0.f;
        const float4* se4 = (const float4*)se;
        const int rb = g * 4;
        for (int k4 = 0; k4 < E_DIM / 4; ++k4) {
            // 4 rows' e-values (broadcast within the 32-lane group -> conflict-free)
            float4 e0 = se4[(rb + 0) * (E_DIM / 4) + k4];
            float4 e1 = se4[(rb + 1) * (E_DIM / 4) + k4];
            float4 e2 = se4[(rb + 2) * (E_DIM / 4) + k4];
            float4 e3 = se4[(rb + 3) * (E_DIM / 4) + k4];
            const int k = k4 * 4;
            // w1 reads: lane-stride-1 across o -> conflict-free
            float wa = sw1[(k + 0) * H1 + o];
            float wb = sw1[(k + 1) * H1 + o];
            float wc = sw1[(k + 2) * H1 + o];
            float wd = sw1[(k + 3) * H1 + o];
            acc0 = fmaf(e0.x, wa, acc0); acc0 = fmaf(e0.y, wb, acc0);
            acc0 = fmaf(e0.z, wc, acc0); acc0 = fmaf(e0.w, wd, acc0);
            acc1 = fmaf(e1.x, wa, acc1); acc1 = fmaf(e1.y, wb, acc1);
            acc1 = fmaf(e1.z, wc, acc1); acc1 = fmaf(e1.w, wd, acc1);
            acc2 = fmaf(e2.x, wa, acc2); acc2 = fmaf(e2.y, wb, acc2);
            acc2 = fmaf(e2.z, wc, acc2); acc2 = fmaf(e2.w, wd, acc2);
            acc3 = fmaf(e3.x, wa, acc3); acc3 = fmaf(e3.y, wb, acc3);
            acc3 = fmaf(e3.z, wc, acc3); acc3 = fmaf(e3.w, wd, acc3);
        }
        const float bo = b1[o];
        sh1[rb + 0][o] = gelu_exact(acc0 + bo);
        sh1[rb + 1][o] = gelu_exact(acc1 + bo);
        sh1[rb + 2][o] = gelu_exact(acc2 + bo);
        sh1[rb + 3][o] = gelu_exact(acc3 + bo);
    }
    __syncthreads();

    // ---- Layer 2: 32 -> 16. thread = (o2 = t&15, rr = t>>4) -> rows rr, rr+16 ----
    {
        const int o2 = t & 15;
        const int rr = t >> 4;
        const float bo = b2[o2];
        #pragma unroll
        for (int h = 0; h < 2; ++h) {
            const int r = rr + 16 * h;
            float a = 0.f;
            #pragma unroll
            for (int k = 0; k < H1; ++k) a = fmaf(sh1[r][k], w2[k * H2 + o2], a);
            sh2[r][o2] = gelu_exact(a + bo);
        }
    }
    __syncthreads();

    // ---- Layer 3: 16 -> 1; sigmoid; c = -0.5/sigma^2 ----
    if (t < R_PER_BLK) {
        float s = 0.f;
        #pragma unroll
        for (int k = 0; k < H2; ++k) s = fmaf(sh2[t][k], w3[k], s);
        const float x = s + b3[0];
        const float sig = 1.0f / (1.0f + __expf(-x));
        const float sigma = 0.1f + 9.9f * sig;
        c_out[row0 + t] = -0.5f / (sigma * sigma);
    }
}

// One block per (b,n) row; 256 threads x 8 m-values each; float4 loads/stores.
__global__ __launch_bounds__(256) void rbf_kernel(
    const float* __restrict__ z, const float* __restrict__ mu,
    const float* __restrict__ c_in, float* __restrict__ out)
{
    const int row = blockIdx.x;
    const int t = threadIdx.x;
    const float c = c_in[row];                 // wave-uniform
    const float mu0 = mu[row * 2 + 0];
    const float mu1 = mu[row * 2 + 1];
    const float4* zf4 = (const float4*)z;      // z[M][2]: float4 j = (z[2j][.], z[2j+1][.])
    float4* out4 = (float4*)out + (size_t)row * (M_TOTAL / 4);

    #pragma unroll
    for (int i = 0; i < 2; ++i) {
        const int idx = i * 256 + t;           // float4 index within the row: 0..511
        const float4 za = zf4[idx * 2 + 0];    // m = 4*idx + {0,1}
        const float4 zb = zf4[idx * 2 + 1];    // m = 4*idx + {2,3}
        float4 r;
        float d0, d1;
        d0 = za.x - mu0; d1 = za.y - mu1;
        r.x = __expf(fmaf(d1, d1, d0 * d0) * c);
        d0 = za.z - mu0; d1 = za.w - mu1;
        r.y = __expf(fmaf(d1, d1, d0 * d0) * c);
        d0 = zb.x - mu0; d1 = zb.y - mu1;
        r.z = __expf(fmaf(d1, d1, d0 * d0) * c);
        d0 = zb.z - mu0; d1 = zb.w - mu1;
        r.w = __expf(fmaf(d1, d1, d0 * d0) * c);
        out4[idx] = r;                         // coalesced 16B stores
    }
}

extern "C" void kernel_launch(void* const* d_in, const int* in_sizes, int n_in,
                              void* d_out, int out_size, void* d_ws, size_t ws_size,
                              hipStream_t stream) {
    const float* z   = (const float*)d_in[0];
    const float* mu  = (const float*)d_in[1];
    const float* emb = (const float*)d_in[2];
    const float* w1  = (const float*)d_in[3];
    const float* b1  = (const float*)d_in[4];
    const float* w2  = (const float*)d_in[5];
    const float* b2  = (const float*)d_in[6];
    const float* w3  = (const float*)d_in[7];
    const float* b3  = (const float*)d_in[8];
    float* out = (float*)d_out;
    float* c_ws = (float*)d_ws;   // 8192 floats = 32 KiB scratch

    sigma_mlp_v2<<<ROWS / R_PER_BLK, 256, 0, stream>>>(emb, w1, b1, w2, b2, w3, b3, c_ws);
    rbf_kernel<<<ROWS, 256, 0, stream>>>(z, mu, c_ws, out);
}